// Round 3
// baseline (361.710 us; speedup 1.0000x reference)
//
#include <hip/hip_runtime.h>

// RegularizedDifferentialLoss on MI355X (gfx950)
// logits [B,N,C] f32, differentials [B,1,G] f32, group_ids [C] i32 (fixed: repeat(arange(G), C/G))
// out: scalar f32 = diff_loss + 0.1 * ce_loss
//
// ce per row  = -max_c log_softmax = logZ - max_c(x)  (computed as log(sum exp(x-m)))
// grouped_g   = sum of softmax p over classes [8g, 8g+8); probs = grouped / sum_g grouped
// avg_probs   = mean over n; t = softmax(differentials); kl = sum t*(log t - log avg)/G
//
// Layout: half-wave per row. Lane l owns group q = (l&31) = classes [8q, 8q+8)
// of row (pair_base + (l>>5)). Group-sum is lane-local; max/sum butterflies use
// xor masks 1..16 so one shuffle instruction serves both rows of the pair.
// Expected regime: HBM-bound (268 MB single pass, ~43 us roofline); DS ~10%,
// trans ~13%, VALU <25% of budget per the cycle model.

#define BB 8
#define NN 32768
#define CC 256
#define GG 32
#define ROWS_PER_WAVE 32
#define PAIRS_PER_WAVE (ROWS_PER_WAVE / 2)
#define WAVES_PER_BLOCK 4
#define BLOCK 256
#define NUM_BLOCKS ((BB * NN) / (ROWS_PER_WAVE * WAVES_PER_BLOCK)) // 2048
#define BLOCKS_PER_BATCH (NUM_BLOCKS / BB)                         // 256

__global__ void zero_ws_kernel(float* __restrict__ ws) {
  int t = threadIdx.x;
  if (t < BB * GG + BB) ws[t] = 0.0f; // S[256] + ceB[8]
}

__global__ __launch_bounds__(BLOCK) void rdl_main_kernel(
    const float* __restrict__ logits,
    float* __restrict__ S,    // [B*G] sum over n of per-row group probs
    float* __restrict__ ceB)  // [B]  sum over n of (logZ - max)
{
  __shared__ float sAcc[GG];
  __shared__ float sCe;
  const int tid = threadIdx.x;
  if (tid < GG) sAcc[tid] = 0.0f;
  if (tid == 0) sCe = 0.0f;
  __syncthreads();

  const int lane = tid & 63;
  const int half = lane >> 5;  // 0: row 2p, 1: row 2p+1
  const int q = lane & 31;     // group index owned by this lane
  const int widx = tid >> 6;
  const int waveg = blockIdx.x * WAVES_PER_BLOCK + widx;
  const long long row0 = (long long)waveg * ROWS_PER_WAVE;

  // lane base: row (row0+half), classes [8q, 8q+8)
  const float* base = logits + (row0 + half) * CC + (q << 3);

  float gAcc = 0.0f;  // accumulated normalized group prob for group q of this half's rows
  float ceAcc = 0.0f; // accumulated log(sum exp(x - m)) = logZ - max

#pragma unroll 4
  for (int p = 0; p < PAIRS_PER_WAVE; ++p) {
    const float* rp = base + (long long)p * (2 * CC);
    const float4 a = *reinterpret_cast<const float4*>(rp);
    const float4 b = *reinterpret_cast<const float4*>(rp + 4);

    // lane-local max of 8 (compiler fuses fmaxf chains into v_max3)
    float m = fmaxf(fmaxf(fmaxf(a.x, a.y), fmaxf(a.z, a.w)),
                    fmaxf(fmaxf(b.x, b.y), fmaxf(b.z, b.w)));
    // row max across the 32-lane half (masks < 32 stay within each half)
#pragma unroll
    for (int off = 1; off < 32; off <<= 1)
      m = fmaxf(m, __shfl_xor(m, off, 64));

    // group sum of exp(x - m): entirely lane-local
    const float g =
        ((__expf(a.x - m) + __expf(a.y - m)) + (__expf(a.z - m) + __expf(a.w - m))) +
        ((__expf(b.x - m) + __expf(b.y - m)) + (__expf(b.z - m) + __expf(b.w - m)));

    // Z = sum over 32 groups (within half)
    float Z = g;
#pragma unroll
    for (int off = 1; off < 32; off <<= 1)
      Z += __shfl_xor(Z, off, 64);

    ceAcc += __logf(Z);                       // logZ - max  (CE term)
    gAcc += g * __builtin_amdgcn_rcpf(Z);     // normalized group prob
  }

  // block-level reduce in LDS (once per wave), then one set of global atomics per block
  atomicAdd(&sAcc[q], gAcc);                          // 2 lanes/address (both halves)
  if (q == 0) atomicAdd(&sCe, ceAcc);                 // lanes 0 and 32
  __syncthreads();

  const int bb = blockIdx.x / BLOCKS_PER_BATCH; // 128 consecutive rows/block -> single batch
  if (tid < GG) atomicAdd(&S[bb * GG + tid], sAcc[tid]);
  if (tid == 0) atomicAdd(&ceB[bb], sCe);
}

__global__ void rdl_final_kernel(const float* __restrict__ S,
                                 const float* __restrict__ ceB,
                                 const float* __restrict__ diff, // [B*G]
                                 float* __restrict__ out) {
  __shared__ float kl[BB];
  const int t = threadIdx.x; // 256 threads: (b,g) = (t>>5, t&31)
  const int b = t >> 5;
  const int g = t & 31;

  const float avg = S[t] * (1.0f / (float)NN);
  const float d = diff[t];

  float m = d;
#pragma unroll
  for (int off = 1; off < 32; off <<= 1)
    m = fmaxf(m, __shfl_xor(m, off, 32));

  const float e = __expf(d - m);
  float Z = e;
#pragma unroll
  for (int off = 1; off < 32; off <<= 1)
    Z += __shfl_xor(Z, off, 32);

  const float logt = (d - m) - __logf(Z);
  const float tprob = e / Z;
  float s = tprob * (logt - __logf(avg));
#pragma unroll
  for (int off = 1; off < 32; off <<= 1)
    s += __shfl_xor(s, off, 32);

  if (g == 0) kl[b] = s * (1.0f / (float)GG);
  __syncthreads();

  if (t == 0) {
    float dsum = 0.0f;
#pragma unroll
    for (int i = 0; i < BB; ++i) dsum += kl[i];
    const float diff_loss = dsum * (1.0f / (float)BB);
    float ce = 0.0f;
#pragma unroll
    for (int i = 0; i < BB; ++i) ce += ceB[i];
    const float ce_loss = ce * (1.0f / ((float)BB * (float)NN));
    out[0] = diff_loss + 0.1f * ce_loss;
  }
}

extern "C" void kernel_launch(void* const* d_in, const int* in_sizes, int n_in,
                              void* d_out, int out_size, void* d_ws, size_t ws_size,
                              hipStream_t stream) {
  const float* logits = (const float*)d_in[0];
  const float* diff = (const float*)d_in[1];
  // d_in[2] = group_ids: fixed pattern repeat(arange(32), 8) — exploited structurally.
  float* ws = (float*)d_ws;
  float* S = ws;             // 256 floats
  float* ceB = ws + BB * GG; // 8 floats
  float* out = (float*)d_out;

  zero_ws_kernel<<<1, 512, 0, stream>>>(ws);
  rdl_main_kernel<<<NUM_BLOCKS, BLOCK, 0, stream>>>(logits, S, ceB);
  rdl_final_kernel<<<1, 256, 0, stream>>>(S, ceB, diff, out);
}